// Round 18
// baseline (620.433 us; speedup 1.0000x reference)
//
#include <hip/hip_runtime.h>
#include <hip/hip_bf16.h>

#define N 2048
#define NN (N * N)

typedef float f4 __attribute__((ext_vector_type(4)));
typedef float f2 __attribute__((ext_vector_type(2)));
typedef unsigned int u32;
typedef u32 u32x4 __attribute__((ext_vector_type(4)));

// ws float offsets (reduction scratch, < 1 MB total)
#define OFF_ROWSUM 0
#define OFF_COLSUM 32768
#define OFF_SUMS   65536      // [0..15]=diagsum, [16..31]=totsum
#define OFF_DIAG   65568
#define OFF_A      98336
#define OFF_B      131104
#define OFF_D      163872
#define OFF_C      196640
// pack area (u32 offsets within ws): XD at 1M u32 (4 MB), XT after XD
#define OFF_XD_U32 (1u << 20)
#define OFF_XT_U32 (OFF_XD_U32 + 4u * NN)
#define WS_NEEDED_BYTES ((size_t)(OFF_XT_U32 + 4u * NN) * 4)

// ---------------- fused pack(fp8) + reduce ----------------
// Block = (32-row slab s0, 64-col panel t0, channel-quad qz).
// Stages [4][32][68] f32 tile (nontemporal X loads); emits XD[qz][x][y] /
// XT[qz][t][s] as u32 of 4 fp8 e4m3 (one per channel) into d_ws, plus
// rowsum/colsum (sparse atomics) and diag.
__global__ __launch_bounds__(256, 4) void packreduce_kernel(const float* __restrict__ X,
                                                            float* __restrict__ ws,
                                                            u32* __restrict__ XD,
                                                            u32* __restrict__ XT) {
    const int s0 = blockIdx.x * 32;    // 64 slabs
    const int t0 = blockIdx.y * 64;    // 32 panels
    const int qz = blockIdx.z;         // 4 channel quads
    const int tid = threadIdx.x;

    __shared__ float lds[4][32][68];

    // stage: 4 ch x 32 rows x 16 f4
    #pragma unroll
    for (int j = 0; j < 8; ++j) {
        const int idx = tid + 256 * j;          // 0..2047
        const int ch = idx >> 9, row = (idx >> 4) & 31, q = idx & 15;
        const f4 v = __builtin_nontemporal_load(
            (const f4*)(X + (size_t)(4 * qz + ch) * NN + (size_t)(s0 + row) * N + t0 + 4 * q));
        *(f4*)&lds[ch][row][4 * q] = v;
    }
    __syncthreads();

    // XD: u32 = fp8(ch0..ch3) per pixel, direct layout
    #pragma unroll
    for (int j = 0; j < 2; ++j) {
        const int idx = tid + 256 * j;          // 0..511
        const int row = idx >> 4, c4 = idx & 15;
        u32x4 w;
        #pragma unroll
        for (int i = 0; i < 4; ++i) {
            const int c = 4 * c4 + i;
            int t = __builtin_amdgcn_cvt_pk_fp8_f32(lds[0][row][c], lds[1][row][c], 0, false);
            t = __builtin_amdgcn_cvt_pk_fp8_f32(lds[2][row][c], lds[3][row][c], t, true);
            w[i] = (u32)t;
        }
        *(u32x4*)(XD + (size_t)qz * NN + (size_t)(s0 + row) * N + t0 + 4 * c4) = w;
    }

    // XT: u32 = fp8(ch0..ch3) per pixel, transposed layout
    #pragma unroll
    for (int j = 0; j < 2; ++j) {
        const int idx = tid + 256 * j;          // 0..511
        const int tt = idx >> 3, sq = idx & 7;
        u32x4 w;
        #pragma unroll
        for (int i = 0; i < 4; ++i) {
            const int s = 4 * sq + i;
            int t = __builtin_amdgcn_cvt_pk_fp8_f32(lds[0][s][tt], lds[1][s][tt], 0, false);
            t = __builtin_amdgcn_cvt_pk_fp8_f32(lds[2][s][tt], lds[3][s][tt], t, true);
            w[i] = (u32)t;
        }
        *(u32x4*)(XT + (size_t)qz * NN + (size_t)(t0 + tt) * N + s0 + 4 * sq) = w;
    }

    // rowsum + diag (threads 0..127: ch = (tid>>5)&3, row = tid&31)
    if (tid < 128) {
        const int ch = (tid >> 5) & 3, row = tid & 31;
        const int c = 4 * qz + ch;
        float rs = 0.f;
        #pragma unroll
        for (int j = 0; j < 16; ++j) {
            const f4 v = *(const f4*)&lds[ch][row][4 * j];
            rs += (v.x + v.y) + (v.z + v.w);
        }
        atomicAdd(&ws[OFF_ROWSUM + c * N + s0 + row], rs);
        const int col = s0 + row - t0;
        if (col >= 0 && col < 64)
            ws[OFF_DIAG + c * N + s0 + row] = lds[ch][row][col];
    }

    // colsum (all 256: ch = tid>>6, col = tid&63)
    {
        const int ch = tid >> 6, col = tid & 63;
        float cs = 0.f;
        #pragma unroll
        for (int r = 0; r < 32; ++r) cs += lds[ch][r][col];
        atomicAdd(&ws[OFF_COLSUM + (4 * qz + ch) * N + t0 + col], cs);
    }
}

// ---------------- sums: diagsum / totsum per channel ----------------
__global__ __launch_bounds__(256) void sums_kernel(float* __restrict__ ws) {
    const int c = blockIdx.x;
    const int tid = threadIdx.x;
    float tot = 0.f, dg = 0.f;
    #pragma unroll
    for (int j = 0; j < 8; ++j) {
        tot += ws[OFF_ROWSUM + c * N + tid + 256 * j];
        dg  += ws[OFF_DIAG   + c * N + tid + 256 * j];
    }
    #pragma unroll
    for (int s = 1; s < 64; s <<= 1) { tot += __shfl_xor(tot, s); dg += __shfl_xor(dg, s); }
    __shared__ float buf[2][4];
    const int wave = tid >> 6, lane = tid & 63;
    if (lane == 0) { buf[0][wave] = tot; buf[1][wave] = dg; }
    __syncthreads();
    if (tid == 0) {
        ws[OFF_SUMS + 16 + c] = buf[0][0] + buf[0][1] + buf[0][2] + buf[0][3];
        ws[OFF_SUMS + c]      = buf[1][0] + buf[1][1] + buf[1][2] + buf[1][3];
    }
}

// ---------------- fold: A, B, D, C ----------------
__global__ __launch_bounds__(256) void fold_kernel(const float* __restrict__ W,
                                                   const float* __restrict__ bias,
                                                   float* __restrict__ ws) {
    const int o = blockIdx.y;
    const int x = blockIdx.x * 256 + threadIdx.x;
    const float invN = 1.f / (float)N;
    const float invN2 = invN * invN;
    const float* rowsum = ws + OFF_ROWSUM;
    const float* colsum = ws + OFF_COLSUM;
    const float* diagv  = ws + OFF_DIAG;
    const float* sums   = ws + OFF_SUMS;
    float* Abuf = ws + OFF_A;
    float* Bbuf = ws + OFF_B;
    float* Dbuf = ws + OFF_D;
    float* Cbuf = ws + OFF_C;

    if (blockIdx.x == 0 && threadIdx.x == 0) {
        float cacc = 0.f;
        #pragma unroll
        for (int c = 0; c < 16; ++c)
            cacc += (sums[c] * invN) * W[11 * 256 + c * 16 + o]
                  + (sums[16 + c] * invN2) * W[14 * 256 + c * 16 + o];
        float sb = 0.f;
        for (int p = 0; p < 15; ++p) sb += bias[p];
        Cbuf[o] = cacc + sb;
    }

    float du = 0.f;
    #pragma unroll
    for (int c = 0; c < 16; ++c)
        du += (sums[c] * invN) * W[2 * 256 + c * 16 + o]
            + (sums[16 + c] * invN2) * W[4 * 256 + c * 16 + o];

    float a = 0.f, b = 0.f, d = 0.f;
    #pragma unroll
    for (int c = 0; c < 16; ++c) {
        const float dg = diagv[c * N + x];
        const float rm = rowsum[c * N + x] * invN;
        const float cm = colsum[c * N + x] * invN;
        a += dg * W[5 * 256 + c * 16 + o] + rm * W[12 * 256 + c * 16 + o] + cm * W[7 * 256 + c * 16 + o];
        b += dg * W[9 * 256 + c * 16 + o] + rm * W[13 * 256 + c * 16 + o] + cm * W[10 * 256 + c * 16 + o];
        d += dg * W[0 * 256 + c * 16 + o] + rm * W[3 * 256 + c * 16 + o]  + cm * W[1 * 256 + c * 16 + o];
    }
    Abuf[o * N + x] = a;
    Bbuf[o * N + x] = b;
    Dbuf[o * N + x] = d + du;
}

// ---------------- main: fully-streaming, fp8 inputs, f4-vector FMA ----------------
// Round-11 inner structure (f4 accumulate -> v_pk_fma_f32 friendly), fed by
// fp8 unpack. Per qz-half: 8 cvts build xa/xb/ta/tb (f4 over the 4 pixels),
// then 32 f4-FMAs with SGPR-uniform weights. Live ~60 VGPR -> no spill.
// Round-17 lesson: scalar per-element accumulate doubled VALU issue (72% busy).
template <bool HI>
__device__ __forceinline__ void fma4(const u32x4& xd, const u32x4& xt,
                                     const float* __restrict__ Wid,
                                     const float* __restrict__ Wtr,
                                     int cA, f4* acc) {
    // channels cA (from .x) and cA+1 (from .y)
    f4 xa, xb, ta, tb;
    #pragma unroll
    for (int i = 0; i < 4; ++i) {
        const f2 d = __builtin_amdgcn_cvt_pk_f32_fp8((int)xd[i], HI);
        const f2 t = __builtin_amdgcn_cvt_pk_f32_fp8((int)xt[i], HI);
        xa[i] = d.x; xb[i] = d.y;
        ta[i] = t.x; tb[i] = t.y;
    }
    const f4 wiA0 = *(const f4*)&Wid[cA * 16];
    const f4 wiA1 = *(const f4*)&Wid[cA * 16 + 4];
    const f4 wiB0 = *(const f4*)&Wid[cA * 16 + 16];
    const f4 wiB1 = *(const f4*)&Wid[cA * 16 + 20];
    const f4 wtA0 = *(const f4*)&Wtr[cA * 16];
    const f4 wtA1 = *(const f4*)&Wtr[cA * 16 + 4];
    const f4 wtB0 = *(const f4*)&Wtr[cA * 16 + 16];
    const f4 wtB1 = *(const f4*)&Wtr[cA * 16 + 20];
    #pragma unroll
    for (int oo = 0; oo < 4; ++oo) {
        acc[oo]     += wiA0[oo] * xa + wiB0[oo] * xb + wtA0[oo] * ta + wtB0[oo] * tb;
        acc[oo + 4] += wiA1[oo] * xa + wiB1[oo] * xb + wtA1[oo] * ta + wtB1[oo] * tb;
    }
}

__global__ __launch_bounds__(256, 4) void main_kernel(const float* __restrict__ W,
                                                      const float* __restrict__ ws,
                                                      const u32* __restrict__ XD,
                                                      const u32* __restrict__ XT,
                                                      float* __restrict__ out) {
    const int tid = threadIdx.x;
    const int og = __builtin_amdgcn_readfirstlane(tid >> 7);
    const int qi = tid & 127;
    const size_t p = ((size_t)blockIdx.x * 128 + qi) * 4;   // pixel flat index
    const int x = (int)(p >> 11);
    const int y = (int)(p & 2047);

    const float* Wid = W + 8 * 256 + og * 8;   // identity partition, o-slice
    const float* Wtr = W + 6 * 256 + og * 8;   // transpose partition, o-slice

    f4 acc[8];
    #pragma unroll
    for (int oo = 0; oo < 8; ++oo) acc[oo] = (f4)(0.f);

    #pragma unroll
    for (int qz = 0; qz < 4; ++qz) {
        const u32x4 xd = *(const u32x4*)(XD + (size_t)qz * NN + p);
        const u32x4 xt = *(const u32x4*)(XT + (size_t)qz * NN + p);
        fma4<false>(xd, xt, Wid, Wtr, 4 * qz,     acc);   // ch 4qz, 4qz+1
        fma4<true >(xd, xt, Wid, Wtr, 4 * qz + 2, acc);   // ch 4qz+2, 4qz+3
    }

    __syncthreads();   // ordering for the out-alias fallback only

    const float* Abuf = ws + OFF_A;
    const float* Bbuf = ws + OFF_B;
    const float* Dbuf = ws + OFF_D;
    const float* Cbuf = ws + OFF_C;

    #pragma unroll
    for (int oo = 0; oo < 8; ++oo) {
        const int o = og * 8 + oo;
        const float av = Abuf[o * N + x] + Cbuf[o];
        const f4 bv = *(const f4*)&Bbuf[o * N + y];
        f4 v = acc[oo] + av + bv;
        const int d = x - y;
        if (d >= 0 && d < 4) v[d] += Dbuf[o * N + x];
        __builtin_nontemporal_store(v, (f4*)(out + (size_t)o * NN + p));
    }
}

extern "C" void kernel_launch(void* const* d_in, const int* in_sizes, int n_in,
                              void* d_out, int out_size, void* d_ws, size_t ws_size,
                              hipStream_t stream) {
    (void)in_sizes; (void)n_in; (void)out_size;
    const float* X    = (const float*)d_in[0];
    const float* W    = (const float*)d_in[1];
    const float* bias = (const float*)d_in[2];
    float* out = (float*)d_out;
    float* ws  = (float*)d_ws;

    u32 *XD, *XT;
    if (ws_size >= WS_NEEDED_BYTES) {            // observed ws_size ~1 GiB
        XD = (u32*)ws + OFF_XD_U32;              // pack lives in scratch
        XT = (u32*)ws + OFF_XT_U32;
    } else {                                     // fallback: alias into out
        XD = (u32*)out;
        XT = (u32*)out + (size_t)4 * NN;
    }

    (void)hipMemsetAsync(ws, 0, (OFF_SUMS + 32) * sizeof(float), stream);   // rowsum+colsum+sums
    packreduce_kernel<<<dim3(64, 32, 4), 256, 0, stream>>>(X, ws, XD, XT);
    sums_kernel<<<16, 256, 0, stream>>>(ws);
    fold_kernel<<<dim3(8, 16), 256, 0, stream>>>(W, bias, ws);
    main_kernel<<<8192, 256, 0, stream>>>(W, ws, XD, XT, out);
}

// Round 19
// 222.387 us; speedup vs baseline: 2.7899x; 2.7899x over previous
//
#include <hip/hip_runtime.h>
#include <hip/hip_bf16.h>

#define N 2048

typedef float f4 __attribute__((ext_vector_type(4)));
typedef unsigned int u32;
typedef u32 u32x4 __attribute__((ext_vector_type(4)));

// ws float offsets
#define OFF_ROWSUM 0
#define OFF_COLSUM 32768
#define OFF_DIAG   65536
#define OFF_SUMS   98304      // [0..15]=diagsum, [16..31]=totsum
#define OFF_A      98336
#define OFF_B      131104
#define OFF_D      163872
#define OFF_C      196640
#define OFF_ROWPART 196656    // 16 panels * 16 c * 2048
#define OFF_COLPART 720944    // 64 slabs  * 16 c * 2048

// ---------------- fused pack + reduce ----------------
// Block = (32-row slab s0, 128-col panel t0, channel-pair cz).
// Stages [2][32][132] f32 tile once (NONTEMPORAL X loads: X is read exactly
// once, keep L3 capacity for the packs); produces:
//   XD[cz][x][y]  bf16-pair DIRECT copy   (-> out channels 0..7)
//   XT[cz][t][s]  bf16-pair TRANSPOSE     (-> out channels 8..15)
//   rowpart / colpart / diag partials (f32, from the staged tile)
__global__ __launch_bounds__(256, 4) void packreduce_kernel(const float* __restrict__ X,
                                                            float* __restrict__ ws,
                                                            u32* __restrict__ XD,
                                                            u32* __restrict__ XT) {
    const int s0 = blockIdx.x * 32;    // 64 slabs
    const int t0 = blockIdx.y * 128;   // 16 panels
    const int cz = blockIdx.z;         // 8 channel pairs
    const int tid = threadIdx.x;

    __shared__ float lds[2][32][132];

    // staging + XD: 1024 (row,c4) quads; each thread loads both channels of one quad
    #pragma unroll
    for (int j = 0; j < 4; ++j) {
        const int idx = tid + 256 * j;           // 0..1023
        const int row = idx >> 5, c4 = idx & 31;
        const float* src = X + (size_t)(2 * cz) * N * N + (size_t)(s0 + row) * N + t0 + 4 * c4;
        const f4 v0 = __builtin_nontemporal_load((const f4*)src);
        const f4 v1 = __builtin_nontemporal_load((const f4*)(src + N * N));
        *(f4*)&lds[0][row][4 * c4] = v0;
        *(f4*)&lds[1][row][4 * c4] = v1;
        u32x4 wd;
        #pragma unroll
        for (int i = 0; i < 4; ++i) {
            const unsigned short lo = __builtin_bit_cast(unsigned short, __float2bfloat16(v0[i]));
            const unsigned short hi = __builtin_bit_cast(unsigned short, __float2bfloat16(v1[i]));
            wd[i] = (u32)lo | ((u32)hi << 16);
        }
        *(u32x4*)(XD + (size_t)cz * N * N + (size_t)(s0 + row) * N + t0 + 4 * c4) = wd;
    }
    __syncthreads();

    // XT write: bf16(ch0) | bf16(ch1)<<16, transposed
    #pragma unroll
    for (int j = 0; j < 4; ++j) {
        const int idx = tid + 256 * j;           // 0..1023 u32x4 chunks
        const int tt = idx >> 3, xq = idx & 7;
        u32x4 w;
        #pragma unroll
        for (int i = 0; i < 4; ++i) {
            const int sl = 4 * xq + i;
            const unsigned short lo = __builtin_bit_cast(unsigned short, __float2bfloat16(lds[0][sl][tt]));
            const unsigned short hi = __builtin_bit_cast(unsigned short, __float2bfloat16(lds[1][sl][tt]));
            w[i] = (u32)lo | ((u32)hi << 16);
        }
        *(u32x4*)(XT + (size_t)cz * N * N + (size_t)(t0 + tt) * N + s0 + 4 * xq) = w;
    }

    // rowpart: 64 (ch,row) pairs x 4 segments of 32 cols
    {
        const int pr = tid >> 2, seg = tid & 3;
        const int ch = pr >> 5, row = pr & 31;
        float rs = 0.f;
        #pragma unroll
        for (int j = 0; j < 8; ++j) {
            const f4 v = *(const f4*)&lds[ch][row][seg * 32 + 4 * j];
            rs += (v.x + v.y) + (v.z + v.w);
        }
        rs += __shfl_xor(rs, 1);
        rs += __shfl_xor(rs, 2);
        if (seg == 0)
            ws[OFF_ROWPART + (size_t)((t0 >> 7) * 16 + 2 * cz + ch) * N + s0 + row] = rs;
    }

    // colpart: 256 (ch,col) pairs, sum 32 rows
    {
        const int ch = tid >> 7, col = tid & 127;
        float cs = 0.f;
        #pragma unroll
        for (int r = 0; r < 32; ++r) cs += lds[ch][r][col];
        ws[OFF_COLPART + (size_t)((s0 >> 5) * 16 + 2 * cz + ch) * N + t0 + col] = cs;
    }

    // diag: tile rows s0+r hit the diagonal when the column lands in this panel
    if (tid < 64) {
        const int ch = tid >> 5, r = tid & 31;
        const int col = s0 + r - t0;
        if (col >= 0 && col < 128)
            ws[OFF_DIAG + (2 * cz + ch) * N + s0 + r] = lds[ch][r][col];
    }
}

// ---------------- rowcolsums: combine partials + per-channel sums ----------------
__global__ __launch_bounds__(256) void rowcolsums_kernel(float* __restrict__ ws) {
    const int c = blockIdx.y;
    const int tid = threadIdx.x;
    const int y = blockIdx.x * 256 + tid;
    float rs = 0.f;
    #pragma unroll
    for (int p = 0; p < 16; ++p) rs += ws[OFF_ROWPART + (size_t)(p * 16 + c) * N + y];
    ws[OFF_ROWSUM + c * N + y] = rs;
    float cs = 0.f;
    #pragma unroll
    for (int s = 0; s < 64; ++s) cs += ws[OFF_COLPART + (size_t)(s * 16 + c) * N + y];
    ws[OFF_COLSUM + c * N + y] = cs;

    if (blockIdx.x == 0) {
        float tot = 0.f, dg = 0.f;
        for (int p = 0; p < 16; ++p)
            #pragma unroll
            for (int j = 0; j < 8; ++j)
                tot += ws[OFF_ROWPART + (size_t)(p * 16 + c) * N + tid + 256 * j];
        #pragma unroll
        for (int j = 0; j < 8; ++j)
            dg += ws[OFF_DIAG + c * N + tid + 256 * j];
        #pragma unroll
        for (int s = 1; s < 64; s <<= 1) { tot += __shfl_xor(tot, s); dg += __shfl_xor(dg, s); }
        __shared__ float buf[2][4];
        const int wave = tid >> 6, lane = tid & 63;
        if (lane == 0) { buf[0][wave] = tot; buf[1][wave] = dg; }
        __syncthreads();
        if (tid == 0) {
            ws[OFF_SUMS + 16 + c] = buf[0][0] + buf[0][1] + buf[0][2] + buf[0][3];
            ws[OFF_SUMS + c]      = buf[1][0] + buf[1][1] + buf[1][2] + buf[1][3];
        }
    }
}

// ---------------- fold: A, B, D, C ----------------
__global__ __launch_bounds__(256) void fold_kernel(const float* __restrict__ W,
                                                   const float* __restrict__ bias,
                                                   float* __restrict__ ws) {
    const int o = blockIdx.y;
    const int x = blockIdx.x * 256 + threadIdx.x;
    const float invN = 1.f / (float)N;
    const float invN2 = invN * invN;
    const float* rowsum = ws + OFF_ROWSUM;
    const float* colsum = ws + OFF_COLSUM;
    const float* diagv  = ws + OFF_DIAG;
    const float* sums   = ws + OFF_SUMS;
    float* Abuf = ws + OFF_A;
    float* Bbuf = ws + OFF_B;
    float* Dbuf = ws + OFF_D;
    float* Cbuf = ws + OFF_C;

    if (blockIdx.x == 0 && threadIdx.x == 0) {
        float cacc = 0.f;
        #pragma unroll
        for (int c = 0; c < 16; ++c)
            cacc += (sums[c] * invN) * W[11 * 256 + c * 16 + o]
                  + (sums[16 + c] * invN2) * W[14 * 256 + c * 16 + o];
        float sb = 0.f;
        for (int p = 0; p < 15; ++p) sb += bias[p];
        Cbuf[o] = cacc + sb;
    }

    float du = 0.f;
    #pragma unroll
    for (int c = 0; c < 16; ++c)
        du += (sums[c] * invN) * W[2 * 256 + c * 16 + o]
            + (sums[16 + c] * invN2) * W[4 * 256 + c * 16 + o];

    float a = 0.f, b = 0.f, d = 0.f;
    #pragma unroll
    for (int c = 0; c < 16; ++c) {
        const float dg = diagv[c * N + x];
        const float rm = rowsum[c * N + x] * invN;
        const float cm = colsum[c * N + x] * invN;
        a += dg * W[5 * 256 + c * 16 + o] + rm * W[12 * 256 + c * 16 + o] + cm * W[7 * 256 + c * 16 + o];
        b += dg * W[9 * 256 + c * 16 + o] + rm * W[13 * 256 + c * 16 + o] + cm * W[10 * 256 + c * 16 + o];
        d += dg * W[0 * 256 + c * 16 + o] + rm * W[3 * 256 + c * 16 + o]  + cm * W[1 * 256 + c * 16 + o];
    }
    Abuf[o * N + x] = a;
    Bbuf[o * N + x] = b;
    Dbuf[o * N + x] = d + du;
}

// ---------------- main: fully-streaming, all-bf16 inputs ----------------
// 256 threads: og = tid>>7 (8 outputs), qi = tid&127 -> f4 pixel-quad.
// Reads ONLY XD+XT (bf16 pairs, 268 MB total, freshly written -> L3-warm).
// XD = out channels 0..7, XT = channels 8..15: each block reads its own
// pixels' packs, __syncthreads, then overwrites them with the real output.
// NONTEMPORAL out stores: avoid sweeping pack lines out of L3.
__global__ __launch_bounds__(256, 4) void main_kernel(const float* __restrict__ W,
                                                      const float* __restrict__ ws,
                                                      const u32* __restrict__ XD,
                                                      const u32* __restrict__ XT,
                                                      float* __restrict__ out) {
    const int tid = threadIdx.x;
    const int og = __builtin_amdgcn_readfirstlane(tid >> 7);
    const int qi = tid & 127;
    const size_t p = ((size_t)blockIdx.x * 128 + qi) * 4;   // pixel flat index
    const int x = (int)(p >> 11);
    const int y = (int)(p & 2047);

    const float* Wid = W + 8 * 256 + og * 8;   // identity partition, o-slice
    const float* Wtr = W + 6 * 256 + og * 8;   // transpose partition, o-slice

    f4 acc[8];
    #pragma unroll
    for (int oo = 0; oo < 8; ++oo) acc[oo] = (f4)(0.f);

    #pragma unroll 4
    for (int c2 = 0; c2 < 8; ++c2) {
        const int c0 = 2 * c2;
        const u32x4 xd = *(const u32x4*)(XD + (size_t)c2 * N * N + p);
        const u32x4 xt = *(const u32x4*)(XT + (size_t)c2 * N * N + p);
        f4 xa, xb, ta, tb;
        #pragma unroll
        for (int i = 0; i < 4; ++i) {
            xa[i] = __builtin_bit_cast(float, xd[i] << 16);
            xb[i] = __builtin_bit_cast(float, xd[i] & 0xffff0000u);
            ta[i] = __builtin_bit_cast(float, xt[i] << 16);
            tb[i] = __builtin_bit_cast(float, xt[i] & 0xffff0000u);
        }
        const f4 wiA0 = *(const f4*)&Wid[c0 * 16];
        const f4 wiA1 = *(const f4*)&Wid[c0 * 16 + 4];
        const f4 wiB0 = *(const f4*)&Wid[c0 * 16 + 16];
        const f4 wiB1 = *(const f4*)&Wid[c0 * 16 + 20];
        const f4 wtA0 = *(const f4*)&Wtr[c0 * 16];
        const f4 wtA1 = *(const f4*)&Wtr[c0 * 16 + 4];
        const f4 wtB0 = *(const f4*)&Wtr[c0 * 16 + 16];
        const f4 wtB1 = *(const f4*)&Wtr[c0 * 16 + 20];
        #pragma unroll
        for (int oo = 0; oo < 4; ++oo) {
            acc[oo]     += wiA0[oo] * xa + wiB0[oo] * xb + wtA0[oo] * ta + wtB0[oo] * tb;
            acc[oo + 4] += wiA1[oo] * xa + wiB1[oo] * xb + wtA1[oo] * ta + wtB1[oo] * tb;
        }
    }

    __syncthreads();   // all XD/XT reads in this block complete before overwrite

    const float* Abuf = ws + OFF_A;
    const float* Bbuf = ws + OFF_B;
    const float* Dbuf = ws + OFF_D;
    const float* Cbuf = ws + OFF_C;

    #pragma unroll
    for (int oo = 0; oo < 8; ++oo) {
        const int o = og * 8 + oo;
        const float av = Abuf[o * N + x] + Cbuf[o];
        const f4 bv = *(const f4*)&Bbuf[o * N + y];
        f4 v = acc[oo] + av + bv;
        const int d = x - y;
        if (d >= 0 && d < 4) v[d] += Dbuf[o * N + x];
        __builtin_nontemporal_store(v, (f4*)(out + (size_t)o * N * N + p));
    }
}

extern "C" void kernel_launch(void* const* d_in, const int* in_sizes, int n_in,
                              void* d_out, int out_size, void* d_ws, size_t ws_size,
                              hipStream_t stream) {
    (void)in_sizes; (void)n_in; (void)out_size; (void)ws_size;
    const float* X    = (const float*)d_in[0];
    const float* W    = (const float*)d_in[1];
    const float* bias = (const float*)d_in[2];
    float* out = (float*)d_out;
    float* ws  = (float*)d_ws;
    u32* XD = (u32*)out;                          // out channels 0..7
    u32* XT = (u32*)(out + (size_t)8 * N * N);    // out channels 8..15

    packreduce_kernel<<<dim3(64, 16, 8), 256, 0, stream>>>(X, ws, XD, XT);
    rowcolsums_kernel<<<dim3(8, 16), 256, 0, stream>>>(ws);
    fold_kernel<<<dim3(8, 16), 256, 0, stream>>>(W, bias, ws);
    main_kernel<<<8192, 256, 0, stream>>>(W, ws, XD, XT, out);
}